// Round 1
// baseline (1153.977 us; speedup 1.0000x reference)
//
#include <hip/hip_runtime.h>
#include <math.h>

// GCN: 2x GraphConv(norm='both') + projection + softmax.
// N=100000 nodes, E=1600000 edges, feats 128 -> 64 -> 64 -> 8.
// All fp32. Workspace usage: (2*N + 2*N*64) floats ~= 52 MB.

#define NODES   100000
#define EDGES   1600000
#define INF     128
#define HID     64
#define OUTF    64
#define NLAB    8

// ---------------- degree / norm ----------------

__global__ void deg_kernel(const int* __restrict__ src, const int* __restrict__ dst,
                           float* __restrict__ deg_out, float* __restrict__ deg_in, int E) {
    int e = blockIdx.x * 256 + threadIdx.x;
    if (e >= E) return;
    atomicAdd(&deg_out[src[e]], 1.0f);
    atomicAdd(&deg_in[dst[e]], 1.0f);
}

__global__ void norm_kernel(float* __restrict__ deg, int n) {
    int i = blockIdx.x * 256 + threadIdx.x;
    if (i >= n) return;
    float d = deg[i];
    d = d < 1.0f ? 1.0f : d;
    deg[i] = rsqrtf(d);
}

// ---------------- GEMM: H[row,col] = norm[row] * sum_k X[row,k]*W[k,col] ----------------
// 256 threads = 4 rows x 64 cols. W staged in LDS (K*64 floats), X rows staged (4*K).

template <int K>
__global__ void gemm_norm_kernel(const float* __restrict__ X, const float* __restrict__ norm,
                                 const float* __restrict__ W, float* __restrict__ H, int M) {
    __shared__ float sW[K * 64];
    __shared__ float sX[4 * K];

    const int tid = threadIdx.x;
    const int col = tid & 63;
    const int rl  = tid >> 6;          // 0..3
    const int row = blockIdx.x * 4 + rl;

    for (int i = tid; i < K * 64; i += 256) sW[i] = W[i];
    for (int i = tid; i < 4 * K; i += 256) {
        int r = blockIdx.x * 4 + i / K;
        sX[i] = (r < M) ? X[(size_t)r * K + (i % K)] : 0.0f;
    }
    __syncthreads();

    if (row >= M) return;
    float acc = 0.0f;
#pragma unroll 16
    for (int k = 0; k < K; ++k)
        acc = fmaf(sX[rl * K + k], sW[k * 64 + col], acc);
    H[(size_t)row * 64 + col] = acc * norm[row];
}

// ---------------- scatter-add: agg[dst,:] += h[src,:] ----------------
// 256 threads = 4 edges x 64 cols, coalesced per edge.

__global__ void scatter_kernel(const int* __restrict__ src, const int* __restrict__ dst,
                               const float* __restrict__ H, float* __restrict__ AGG, int E) {
    int e = blockIdx.x * 4 + (threadIdx.x >> 6);
    int c = threadIdx.x & 63;
    if (e >= E) return;
    int s = src[e];
    int d = dst[e];
    atomicAdd(&AGG[(size_t)d * 64 + c], H[(size_t)s * 64 + c]);
}

// ---------------- epilogue: x = relu(agg * norm_dst[row] + b[col]) in place ----------------

__global__ void bias_relu_kernel(float* __restrict__ AGG, const float* __restrict__ norm,
                                 const float* __restrict__ b, int M) {
    int i = blockIdx.x * 256 + threadIdx.x;
    if (i >= M * 64) return;
    int row = i >> 6;
    int col = i & 63;
    float v = fmaf(AGG[i], norm[row], b[col]);
    AGG[i] = v > 0.0f ? v : 0.0f;
}

// ---------------- projection (64x8) + softmax, one row per thread ----------------

__global__ void proj_softmax_kernel(const float* __restrict__ X, const float* __restrict__ Wp,
                                    const float* __restrict__ bp, float* __restrict__ out, int M) {
    int row = blockIdx.x * 256 + threadIdx.x;
    if (row >= M) return;
    const float* x = X + (size_t)row * 64;

    float logit[NLAB];
#pragma unroll
    for (int l = 0; l < NLAB; ++l) logit[l] = bp[l];
    for (int k = 0; k < 64; ++k) {
        float xv = x[k];
#pragma unroll
        for (int l = 0; l < NLAB; ++l)
            logit[l] = fmaf(xv, Wp[k * NLAB + l], logit[l]);
    }
    float mx = logit[0];
#pragma unroll
    for (int l = 1; l < NLAB; ++l) mx = fmaxf(mx, logit[l]);
    float s = 0.0f;
#pragma unroll
    for (int l = 0; l < NLAB; ++l) { logit[l] = expf(logit[l] - mx); s += logit[l]; }
    float inv = 1.0f / s;
#pragma unroll
    for (int l = 0; l < NLAB; ++l) out[(size_t)row * NLAB + l] = logit[l] * inv;
}

// ---------------- launch ----------------

extern "C" void kernel_launch(void* const* d_in, const int* in_sizes, int n_in,
                              void* d_out, int out_size, void* d_ws, size_t ws_size,
                              hipStream_t stream) {
    const float* features = (const float*)d_in[0];
    const int*   edge_src = (const int*)d_in[1];
    const int*   edge_dst = (const int*)d_in[2];
    // d_in[3] edge_types: unused by reference
    const float* W1 = (const float*)d_in[4];
    const float* b1 = (const float*)d_in[5];
    const float* W2 = (const float*)d_in[6];
    const float* b2 = (const float*)d_in[7];
    const float* Wp = (const float*)d_in[8];
    const float* bp = (const float*)d_in[9];
    float* out = (float*)d_out;

    const int N = NODES;
    const int E = in_sizes[1];

    // workspace layout
    float* ws       = (float*)d_ws;
    float* norm_src = ws;                        // N  (deg_out then norm)
    float* norm_dst = ws + N;                    // N  (deg_in then norm)
    float* h        = ws + 2 * (size_t)N;        // N*64
    float* agg      = h + (size_t)N * 64;        // N*64 (becomes x after epilogue)

    // degrees -> norms
    hipMemsetAsync(norm_src, 0, 2 * (size_t)N * sizeof(float), stream);
    deg_kernel<<<(E + 255) / 256, 256, 0, stream>>>(edge_src, edge_dst, norm_src, norm_dst, E);
    norm_kernel<<<(2 * N + 255) / 256, 256, 0, stream>>>(norm_src, 2 * N);

    // ---- layer 1 ----
    gemm_norm_kernel<INF><<<(N + 3) / 4, 256, 0, stream>>>(features, norm_src, W1, h, N);
    hipMemsetAsync(agg, 0, (size_t)N * 64 * sizeof(float), stream);
    scatter_kernel<<<(E + 3) / 4, 256, 0, stream>>>(edge_src, edge_dst, h, agg, E);
    bias_relu_kernel<<<(N * 64 + 255) / 256, 256, 0, stream>>>(agg, norm_dst, b1, N);

    // ---- layer 2 ---- (x1 lives in agg; gemm reads it before agg is re-zeroed)
    gemm_norm_kernel<HID><<<(N + 3) / 4, 256, 0, stream>>>(agg, norm_src, W2, h, N);
    hipMemsetAsync(agg, 0, (size_t)N * 64 * sizeof(float), stream);
    scatter_kernel<<<(E + 3) / 4, 256, 0, stream>>>(edge_src, edge_dst, h, agg, E);
    bias_relu_kernel<<<(N * 64 + 255) / 256, 256, 0, stream>>>(agg, norm_dst, b2, N);

    // ---- projection + softmax ----
    proj_softmax_kernel<<<(N + 255) / 256, 256, 0, stream>>>(agg, Wp, bp, out, N);
}

// Round 2
// 562.419 us; speedup vs baseline: 2.0518x; 2.0518x over previous
//
#include <hip/hip_runtime.h>
#include <math.h>

// GCN: 2x GraphConv(norm='both') + projection + softmax.
// N=100000 nodes, E=1600000 edges, feats 128 -> 64 -> 64 -> 8. All fp32.
//
// R1 rewrite: scatter-atomic aggregation (400 MB HBM atomic writes, 345 us x2)
// replaced by per-call CSR build + wave-per-node pull gather (no float atomics,
// 25.6 MB writes). Epilogue (norm_dst, bias, relu) fused into gather.

#define NODES   100000
#define INF     128
#define HID     64
#define NLAB    8

// ---------------- degree histogram (int atomics) ----------------

__global__ void deg_kernel(const int* __restrict__ src, const int* __restrict__ dst,
                           int* __restrict__ deg_o, int* __restrict__ deg_i, int E) {
    int e = blockIdx.x * 256 + threadIdx.x;
    if (e >= E) return;
    atomicAdd(&deg_o[src[e]], 1);
    atomicAdd(&deg_i[dst[e]], 1);
}

// ---------------- norms ----------------

__global__ void norm_kernel(const int* __restrict__ deg_o, const int* __restrict__ deg_i,
                            float* __restrict__ ns, float* __restrict__ nd, int n) {
    int i = blockIdx.x * 256 + threadIdx.x;
    if (i >= n) return;
    ns[i] = rsqrtf(fmaxf((float)deg_o[i], 1.0f));
    nd[i] = rsqrtf(fmaxf((float)deg_i[i], 1.0f));
}

// ---------------- exclusive scan of deg_i -> offsets (3 kernels) ----------------

__global__ void scan1_kernel(const int* __restrict__ deg, int* __restrict__ offs,
                             int* __restrict__ aux, int n) {
    __shared__ int s[256];
    int t = threadIdx.x;
    int i = blockIdx.x * 256 + t;
    int v = (i < n) ? deg[i] : 0;
    s[t] = v;
    __syncthreads();
    for (int off = 1; off < 256; off <<= 1) {
        int add = (t >= off) ? s[t - off] : 0;
        __syncthreads();
        s[t] += add;
        __syncthreads();
    }
    if (i < n) offs[i] = s[t] - v;              // exclusive
    if (t == 255) aux[blockIdx.x] = s[255];     // block total
}

__global__ void scan2_kernel(int* __restrict__ aux, int nb) {
    __shared__ int s[512];
    int t = threadIdx.x;
    int v = (t < nb) ? aux[t] : 0;
    s[t] = v;
    __syncthreads();
    for (int off = 1; off < 512; off <<= 1) {
        int add = (t >= off) ? s[t - off] : 0;
        __syncthreads();
        s[t] += add;
        __syncthreads();
    }
    if (t < nb) aux[t] = s[t] - v;              // exclusive block offsets
}

__global__ void scan3_kernel(int* __restrict__ offs, int* __restrict__ cursor,
                             const int* __restrict__ aux, int n, int E) {
    int i = blockIdx.x * 256 + threadIdx.x;
    if (i == 0) offs[n] = E;
    if (i >= n) return;
    int v = offs[i] + aux[blockIdx.x];
    offs[i] = v;
    cursor[i] = v;
}

// ---------------- bucket fill: csr[] = src ids grouped by dst ----------------

__global__ void fill_kernel(const int* __restrict__ src, const int* __restrict__ dst,
                            int* __restrict__ cursor, int* __restrict__ csr, int E) {
    int e = blockIdx.x * 256 + threadIdx.x;
    if (e >= E) return;
    int pos = atomicAdd(&cursor[dst[e]], 1);
    csr[pos] = src[e];
}

// ---------------- GEMM: H[row,:] = norm[row] * (X[row,:] @ W) ----------------
// 256 threads: 16 rows x 16 col-groups (float4 cols). W + X staged in LDS.

template <int K>
__global__ void gemm_norm_kernel(const float* __restrict__ X, const float* __restrict__ norm,
                                 const float* __restrict__ W, float* __restrict__ H, int M) {
    constexpr int KS = K + 4;                   // row pad: kills 4-way bank conflict on sX
    __shared__ float sW[K * 64];
    __shared__ float sX[16 * KS];

    const int tid = threadIdx.x;
    const int row0 = blockIdx.x * 16;

    // stage W (K*64 floats, contiguous) as float4
    for (int i = tid; i < K * 16; i += 256)
        ((float4*)sW)[i] = ((const float4*)W)[i];
    // stage 16 X rows (K floats each) as float4 into padded rows
    for (int i = tid; i < 4 * K; i += 256) {
        int eo = i * 4;
        int r = eo / K, k = eo % K;
        int gr = row0 + r;
        float4 v = (gr < M) ? ((const float4*)(X + (size_t)gr * K))[k >> 2]
                            : make_float4(0.f, 0.f, 0.f, 0.f);
        ((float4*)(sX + r * KS))[k >> 2] = v;
    }
    __syncthreads();

    const int c4 = tid & 15;                    // col group (4 cols)
    const int r  = tid >> 4;                    // 0..15
    const int grow = row0 + r;
    const float* xr = sX + r * KS;

    float4 acc = make_float4(0.f, 0.f, 0.f, 0.f);
#pragma unroll 8
    for (int k = 0; k < K; ++k) {
        float xv = xr[k];                       // broadcast within row group
        float4 w = ((const float4*)(sW + k * 64))[c4];
        acc.x = fmaf(xv, w.x, acc.x);
        acc.y = fmaf(xv, w.y, acc.y);
        acc.z = fmaf(xv, w.z, acc.z);
        acc.w = fmaf(xv, w.w, acc.w);
    }
    if (grow < M) {
        float nm = norm[grow];
        acc.x *= nm; acc.y *= nm; acc.z *= nm; acc.w *= nm;
        ((float4*)(H + (size_t)grow * 64))[c4] = acc;
    }
}

// ---------------- pull gather + fused epilogue ----------------
// One wave per dst node. Quarter q handles edges i = start+q, start+q+4, ...;
// lane-in-quarter c reads float4 cols 4c..4c+3. Cross-quarter shfl reduce.
// X[n,:] = relu(norm_dst[n] * sum_{s in bucket(n)} H[s,:] + b)

__global__ void gather_kernel(const int* __restrict__ offs, const int* __restrict__ csr,
                              const float* __restrict__ H, const float* __restrict__ nd,
                              const float* __restrict__ b, float* __restrict__ X, int Nn) {
    int node = blockIdx.x * 4 + (threadIdx.x >> 6);
    if (node >= Nn) return;                     // wave-uniform
    int lane = threadIdx.x & 63;
    int q = lane >> 4, c = lane & 15;

    int start = offs[node], end = offs[node + 1];
    float4 acc = make_float4(0.f, 0.f, 0.f, 0.f);
    for (int i = start + q; i < end; i += 4) {
        int s = csr[i];
        float4 v = ((const float4*)(H + (size_t)s * 64))[c];
        acc.x += v.x; acc.y += v.y; acc.z += v.z; acc.w += v.w;
    }
    // reduce across quarters (lanes differing in bits 4,5)
#pragma unroll
    for (int m = 16; m <= 32; m <<= 1) {
        acc.x += __shfl_xor(acc.x, m, 64);
        acc.y += __shfl_xor(acc.y, m, 64);
        acc.z += __shfl_xor(acc.z, m, 64);
        acc.w += __shfl_xor(acc.w, m, 64);
    }
    if (q == 0) {
        float nm = nd[node];
        float4 bb = ((const float4*)b)[c];
        float4 r;
        r.x = fmaxf(fmaf(acc.x, nm, bb.x), 0.f);
        r.y = fmaxf(fmaf(acc.y, nm, bb.y), 0.f);
        r.z = fmaxf(fmaf(acc.z, nm, bb.z), 0.f);
        r.w = fmaxf(fmaf(acc.w, nm, bb.w), 0.f);
        ((float4*)(X + (size_t)node * 64))[c] = r;
    }
}

// ---------------- projection (64x8) + softmax, one row per thread ----------------

__global__ void proj_softmax_kernel(const float* __restrict__ X, const float* __restrict__ Wp,
                                    const float* __restrict__ bp, float* __restrict__ out, int M) {
    __shared__ float sW[64 * NLAB];
    __shared__ float sb[NLAB];
    int tid = threadIdx.x;
    for (int i = tid; i < 64 * NLAB; i += 256) sW[i] = Wp[i];
    if (tid < NLAB) sb[tid] = bp[tid];
    __syncthreads();

    int row = blockIdx.x * 256 + tid;
    if (row >= M) return;

    float logit[NLAB];
#pragma unroll
    for (int l = 0; l < NLAB; ++l) logit[l] = sb[l];
    const float4* x4 = (const float4*)(X + (size_t)row * 64);
#pragma unroll 4
    for (int kk = 0; kk < 16; ++kk) {
        float4 v = x4[kk];
        const float xs[4] = {v.x, v.y, v.z, v.w};
#pragma unroll
        for (int j = 0; j < 4; ++j) {
            int k = kk * 4 + j;
            float xv = xs[j];
#pragma unroll
            for (int l = 0; l < NLAB; ++l)
                logit[l] = fmaf(xv, sW[k * NLAB + l], logit[l]);
        }
    }
    float mx = logit[0];
#pragma unroll
    for (int l = 1; l < NLAB; ++l) mx = fmaxf(mx, logit[l]);
    float s = 0.0f;
#pragma unroll
    for (int l = 0; l < NLAB; ++l) { logit[l] = __expf(logit[l] - mx); s += logit[l]; }
    float inv = 1.0f / s;
#pragma unroll
    for (int l = 0; l < NLAB; ++l) out[(size_t)row * NLAB + l] = logit[l] * inv;
}

// ---------------- launch ----------------

extern "C" void kernel_launch(void* const* d_in, const int* in_sizes, int n_in,
                              void* d_out, int out_size, void* d_ws, size_t ws_size,
                              hipStream_t stream) {
    const float* features = (const float*)d_in[0];
    const int*   edge_src = (const int*)d_in[1];
    const int*   edge_dst = (const int*)d_in[2];
    // d_in[3] edge_types: unused by reference
    const float* W1 = (const float*)d_in[4];
    const float* b1 = (const float*)d_in[5];
    const float* W2 = (const float*)d_in[6];
    const float* b2 = (const float*)d_in[7];
    const float* Wp = (const float*)d_in[8];
    const float* bp = (const float*)d_in[9];
    float* out = (float*)d_out;

    const int N = NODES;
    const int E = in_sizes[1];
    const int nb = (N + 255) / 256;             // 391 scan blocks (<= 512)

    // ---- workspace layout (ints then floats), ~60.5 MB total ----
    char* p = (char*)d_ws;
    int*   deg_o  = (int*)p;            p += sizeof(int) * N;
    int*   deg_i  = (int*)p;            p += sizeof(int) * N;
    int*   offs   = (int*)p;            p += sizeof(int) * (N + 1);
    int*   cursor = (int*)p;            p += sizeof(int) * N;
    int*   aux    = (int*)p;            p += sizeof(int) * 512;
    int*   csr    = (int*)p;            p += sizeof(int) * (size_t)E;
    p = (char*)(((size_t)p + 15) & ~(size_t)15);
    float* norm_s = (float*)p;          p += sizeof(float) * N;
    float* norm_d = (float*)p;          p += sizeof(float) * N;
    p = (char*)(((size_t)p + 255) & ~(size_t)255);
    float* h      = (float*)p;          p += sizeof(float) * (size_t)N * 64;
    float* x      = (float*)p;          p += sizeof(float) * (size_t)N * 64;

    // ---- CSR build + norms ----
    hipMemsetAsync(deg_o, 0, sizeof(int) * 2 * (size_t)N, stream);
    deg_kernel<<<(E + 255) / 256, 256, 0, stream>>>(edge_src, edge_dst, deg_o, deg_i, E);
    scan1_kernel<<<nb, 256, 0, stream>>>(deg_i, offs, aux, N);
    scan2_kernel<<<1, 512, 0, stream>>>(aux, nb);
    scan3_kernel<<<nb, 256, 0, stream>>>(offs, cursor, aux, N, E);
    norm_kernel<<<nb, 256, 0, stream>>>(deg_o, deg_i, norm_s, norm_d, N);
    fill_kernel<<<(E + 255) / 256, 256, 0, stream>>>(edge_src, edge_dst, cursor, csr, E);

    // ---- layer 1 ----
    gemm_norm_kernel<INF><<<(N + 15) / 16, 256, 0, stream>>>(features, norm_s, W1, h, N);
    gather_kernel<<<(N + 3) / 4, 256, 0, stream>>>(offs, csr, h, norm_d, b1, x, N);

    // ---- layer 2 ----
    gemm_norm_kernel<HID><<<(N + 15) / 16, 256, 0, stream>>>(x, norm_s, W2, h, N);
    gather_kernel<<<(N + 3) / 4, 256, 0, stream>>>(offs, csr, h, norm_d, b2, x, N);

    // ---- projection + softmax ----
    proj_softmax_kernel<<<(N + 255) / 256, 256, 0, stream>>>(x, Wp, bp, out, N);
}